// Round 1
// baseline (450.009 us; speedup 1.0000x reference)
//
#include <hip/hip_runtime.h>
#include <hip/hip_bf16.h>

typedef __bf16 bf16x8 __attribute__((ext_vector_type(8)));
typedef __bf16 bf16x4v __attribute__((ext_vector_type(4)));
typedef float f32x4 __attribute__((ext_vector_type(4)));

#define DMODEL 2048
#define NH 16
#define HD 128
#define PLEN 512
#define QLEN 2048
#define KVLEN 2560

__device__ __forceinline__ void gload_lds16(const void* g, void* l) {
  __builtin_amdgcn_global_load_lds((const __attribute__((address_space(1))) void*)g,
                                   (__attribute__((address_space(3))) void*)l, 16, 0, 0);
}

// ---------------- conversion kernels ----------------

// f32 [2048][2048] row-major -> bf16 transposed [2048][2048]
__global__ __launch_bounds__(256) void k_transpose_bf16(const float* __restrict__ in,
                                                        __bf16* __restrict__ out) {
  __shared__ float tile[64][65];
  const int t = threadIdx.x;
  const int tx = t & 63, ty = t >> 6;
  const int r0 = blockIdx.y * 64, c0 = blockIdx.x * 64;
#pragma unroll
  for (int i = 0; i < 16; ++i) {
    int r = ty + i * 4;
    tile[r][tx] = in[(size_t)(r0 + r) * DMODEL + c0 + tx];
  }
  __syncthreads();
#pragma unroll
  for (int i = 0; i < 16; ++i) {
    int r = ty + i * 4;
    out[(size_t)(c0 + r) * DMODEL + r0 + tx] = (__bf16)tile[tx][r];
  }
}

__global__ __launch_bounds__(256) void k_f32_to_bf16(const float* __restrict__ in,
                                                     __bf16* __restrict__ out, int n4) {
  int i = blockIdx.x * blockDim.x + threadIdx.x;
  int stride = gridDim.x * blockDim.x;
  for (; i < n4; i += stride) {
    float4 v = ((const float4*)in)[i];
    bf16x4v o;
    o[0] = (__bf16)v.x; o[1] = (__bf16)v.y; o[2] = (__bf16)v.z; o[3] = (__bf16)v.w;
    ((bf16x4v*)out)[i] = o;
  }
}

// prefix_key/value f32 [512][16][128] -> K[h][p][hd], VT[h][hd][p]  (bf16)
__global__ __launch_bounds__(256) void k_prefix(const float* __restrict__ pk,
                                                const float* __restrict__ pv,
                                                __bf16* __restrict__ Kall,
                                                __bf16* __restrict__ VT) {
  int idx = blockIdx.x * 256 + threadIdx.x;  // 512*16*128 = 1048576 exact
  int hd = idx & 127;
  int h = (idx >> 7) & 15;
  int p = idx >> 11;
  Kall[(size_t)h * KVLEN * HD + (size_t)p * HD + hd] = (__bf16)pk[idx];
  VT[(size_t)h * HD * KVLEN + (size_t)hd * KVLEN + p] = (__bf16)pv[idx];
}

// ---------------- GEMM: C[128x128] = A[M,K] * BT[N,K]^T ----------------

__device__ __forceinline__ void gemm_mainloop(const __bf16* __restrict__ A,
                                              const __bf16* __restrict__ BT,
                                              __bf16* Asm, __bf16* Bsm,
                                              int m0, int n0, int w, int l,
                                              f32x4 (&acc)[4][4]) {
  const int lr = l & 15, lg = l >> 4;
  const int lin0 = w * 2048 + l * 16;      // byte offset in 8KB tile
  const int rowS = lin0 >> 6;              // 64B per row (32 bf16)
  const int colS = (lin0 & 63) >> 1;       // element offset within row
  for (int k0 = 0; k0 < DMODEL; k0 += 32) {
    __syncthreads();
#pragma unroll
    for (int i = 0; i < 2; ++i) {
      const __bf16* ga = A + (size_t)(m0 + rowS + i * 16) * DMODEL + k0 + colS;
      gload_lds16(ga, (char*)Asm + w * 2048 + i * 1024);
      const __bf16* gb = BT + (size_t)(n0 + rowS + i * 16) * DMODEL + k0 + colS;
      gload_lds16(gb, (char*)Bsm + w * 2048 + i * 1024);
    }
    __syncthreads();
    bf16x8 af[4], bfv[4];
#pragma unroll
    for (int mi = 0; mi < 4; ++mi)
      af[mi] = *(const bf16x8*)(Asm + ((w >> 1) * 64 + mi * 16 + lr) * 32 + lg * 8);
#pragma unroll
    for (int ni = 0; ni < 4; ++ni)
      bfv[ni] = *(const bf16x8*)(Bsm + ((w & 1) * 64 + ni * 16 + lr) * 32 + lg * 8);
#pragma unroll
    for (int mi = 0; mi < 4; ++mi)
#pragma unroll
      for (int ni = 0; ni < 4; ++ni)
        acc[mi][ni] = __builtin_amdgcn_mfma_f32_16x16x32_bf16(af[mi], bfv[ni], acc[mi][ni], 0, 0, 0);
  }
}

// z=0: Q (scaled 1/sqrt(128)) -> Qs[h][q][hd]; z=1: K -> Kall[h][512+q][hd]; z=2: V -> VT[h][hd][512+q]
__global__ __launch_bounds__(256) void gemm_qkv(const __bf16* __restrict__ xb,
                                                const __bf16* __restrict__ WqT,
                                                const __bf16* __restrict__ WkT,
                                                const __bf16* __restrict__ WvT,
                                                const float* __restrict__ bq,
                                                const float* __restrict__ bk,
                                                const float* __restrict__ bv,
                                                __bf16* __restrict__ Qs,
                                                __bf16* __restrict__ Kall,
                                                __bf16* __restrict__ VT) {
  __shared__ __bf16 Asm[4096];
  __shared__ __bf16 Bsm[4096];
  const int t = threadIdx.x, w = t >> 6, l = t & 63;
  const int m0 = blockIdx.x * 128, n0 = blockIdx.y * 128;
  const int z = blockIdx.z;
  const __bf16* BT = (z == 0) ? WqT : ((z == 1) ? WkT : WvT);
  const float* bias = (z == 0) ? bq : ((z == 1) ? bk : bv);
  f32x4 acc[4][4];
#pragma unroll
  for (int mi = 0; mi < 4; ++mi)
#pragma unroll
    for (int ni = 0; ni < 4; ++ni) acc[mi][ni] = (f32x4){0.f, 0.f, 0.f, 0.f};
  gemm_mainloop(xb, BT, Asm, Bsm, m0, n0, w, l, acc);
  const int lr = l & 15, lg = l >> 4;
#pragma unroll
  for (int mi = 0; mi < 4; ++mi)
#pragma unroll
    for (int ni = 0; ni < 4; ++ni)
#pragma unroll
      for (int r = 0; r < 4; ++r) {
        int row = m0 + (w >> 1) * 64 + mi * 16 + lg * 4 + r;
        int col = n0 + (w & 1) * 64 + ni * 16 + lr;
        float v = acc[mi][ni][r] + bias[col];
        int hh = col >> 7, hd = col & 127;
        if (z == 0) {
          Qs[(size_t)hh * QLEN * HD + (size_t)row * HD + hd] = (__bf16)(v * 0.08838834764831845f);
        } else if (z == 1) {
          Kall[(size_t)hh * KVLEN * HD + (size_t)(PLEN + row) * HD + hd] = (__bf16)v;
        } else {
          VT[(size_t)hh * HD * KVLEN + (size_t)hd * KVLEN + (PLEN + row)] = (__bf16)v;
        }
      }
}

// final: out[q][d] = O[q][:] . WoT[d][:] + bout[d]  (f32 out)
__global__ __launch_bounds__(256) void gemm_out(const __bf16* __restrict__ Ob,
                                                const __bf16* __restrict__ WoT,
                                                const float* __restrict__ bout,
                                                float* __restrict__ out) {
  __shared__ __bf16 Asm[4096];
  __shared__ __bf16 Bsm[4096];
  const int t = threadIdx.x, w = t >> 6, l = t & 63;
  const int m0 = blockIdx.x * 128, n0 = blockIdx.y * 128;
  f32x4 acc[4][4];
#pragma unroll
  for (int mi = 0; mi < 4; ++mi)
#pragma unroll
    for (int ni = 0; ni < 4; ++ni) acc[mi][ni] = (f32x4){0.f, 0.f, 0.f, 0.f};
  gemm_mainloop(Ob, WoT, Asm, Bsm, m0, n0, w, l, acc);
  const int lr = l & 15, lg = l >> 4;
#pragma unroll
  for (int mi = 0; mi < 4; ++mi)
#pragma unroll
    for (int ni = 0; ni < 4; ++ni)
#pragma unroll
      for (int r = 0; r < 4; ++r) {
        int row = m0 + (w >> 1) * 64 + mi * 16 + lg * 4 + r;
        int col = n0 + (w & 1) * 64 + ni * 16 + lr;
        out[(size_t)row * DMODEL + col] = acc[mi][ni][r] + bout[col];
      }
}

// ---------------- attention ----------------
// grid (32, 16): blockIdx.x = q-tile of 64 rows, blockIdx.y = head.
// 4 waves/block, each wave owns 16 q rows. Fixed-max softmax: |logit| <= ~12
// guaranteed (q pre-scaled by 1/sqrt(128), Cauchy-Schwarz), so exp(S-16) is safe.
__global__ __launch_bounds__(256) void k_attn(const __bf16* __restrict__ Qs,
                                              const __bf16* __restrict__ Kall,
                                              const __bf16* __restrict__ VT,
                                              const float* __restrict__ gate,
                                              __bf16* __restrict__ Ob) {
  __shared__ __bf16 Pl[4][512];
  const int h = blockIdx.y;
  const int t = threadIdx.x, w = t >> 6, l = t & 63;
  const int lr = l & 15, lg = l >> 4;
  const int q0 = blockIdx.x * 64 + w * 16;
  const __bf16* Qh = Qs + (size_t)h * QLEN * HD;
  const __bf16* Kh = Kall + (size_t)h * KVLEN * HD;
  const __bf16* Vh = VT + (size_t)h * HD * KVLEN;
  __bf16* Pw = &Pl[w][0];

  bf16x8 qf[4];
#pragma unroll
  for (int c = 0; c < 4; ++c)
    qf[c] = *(const bf16x8*)(Qh + (size_t)(q0 + lr) * HD + c * 32 + lg * 8);

  f32x4 acc1[8], acc2[8];
  float s1[4] = {0.f, 0.f, 0.f, 0.f}, s2[4] = {0.f, 0.f, 0.f, 0.f};
#pragma unroll
  for (int c = 0; c < 8; ++c) {
    acc1[c] = (f32x4){0.f, 0.f, 0.f, 0.f};
    acc2[c] = (f32x4){0.f, 0.f, 0.f, 0.f};
  }

#define ATT_TILE(Kb, Vb, kb, DOMASK, ACC, SS)                                          \
  do {                                                                                 \
    f32x4 st0 = {0.f, 0.f, 0.f, 0.f}, st1 = {0.f, 0.f, 0.f, 0.f};                      \
    _Pragma("unroll") for (int c = 0; c < 4; ++c) {                                    \
      bf16x8 kf0 = *(const bf16x8*)((Kb) + (size_t)((kb) + lr) * HD + c * 32 + lg * 8);\
      bf16x8 kf1 = *(const bf16x8*)((Kb) + (size_t)((kb) + 16 + lr) * HD + c * 32 + lg * 8); \
      st0 = __builtin_amdgcn_mfma_f32_16x16x32_bf16(qf[c], kf0, st0, 0, 0, 0);         \
      st1 = __builtin_amdgcn_mfma_f32_16x16x32_bf16(qf[c], kf1, st1, 0, 0, 0);         \
    }                                                                                  \
    _Pragma("unroll") for (int r = 0; r < 4; ++r) {                                    \
      if (DOMASK) {                                                                    \
        int qq = q0 + lg * 4 + r;                                                      \
        if ((kb) + lr > qq) st0[r] = -1e30f;                                           \
        if ((kb) + 16 + lr > qq) st1[r] = -1e30f;                                      \
      }                                                                                \
      float p0 = __expf(st0[r] - 16.0f);                                               \
      float p1 = __expf(st1[r] - 16.0f);                                               \
      float ps = p0 + p1;                                                              \
      ps += __shfl_xor(ps, 1); ps += __shfl_xor(ps, 2);                                \
      ps += __shfl_xor(ps, 4); ps += __shfl_xor(ps, 8);                                \
      SS[r] += ps;                                                                     \
      Pw[(lg * 4 + r) * 32 + lr] = (__bf16)p0;                                         \
      Pw[(lg * 4 + r) * 32 + 16 + lr] = (__bf16)p1;                                    \
    }                                                                                  \
    bf16x8 pf = *(const bf16x8*)(Pw + lr * 32 + lg * 8);                               \
    _Pragma("unroll") for (int c = 0; c < 8; ++c) {                                    \
      bf16x8 vf = *(const bf16x8*)((Vb) + (size_t)(c * 16 + lr) * KVLEN + (kb) + lg * 8); \
      ACC[c] = __builtin_amdgcn_mfma_f32_16x16x32_bf16(pf, vf, ACC[c], 0, 0, 0);       \
    }                                                                                  \
  } while (0)

  // ---- phase 1: prefix (512 keys, unmasked) ----
  for (int kb = 0; kb < PLEN; kb += 32) ATT_TILE(Kh, Vh, kb, false, acc1, s1);

  // ---- phase 2: causal suffix ----
  const __bf16* Kh2 = Kh + (size_t)PLEN * HD;
  const __bf16* Vh2 = Vh + PLEN;
  const int ntile = (q0 + 47) >> 5;  // tiles with start <= q0+15
  for (int kb = 0; kb < ntile * 32; kb += 32) {
    const bool dm = (kb + 31 > q0);
    ATT_TILE(Kh2, Vh2, kb, dm, acc2, s2);
  }
#undef ATT_TILE

  const float g = gate[h];
#pragma unroll
  for (int r = 0; r < 4; ++r) {
    const float f1 = g / s1[r];
    const float f2 = 1.0f / s2[r];
    const int qrow = q0 + lg * 4 + r;
#pragma unroll
    for (int c = 0; c < 8; ++c) {
      float val = acc1[c][r] * f1 + acc2[c][r] * f2;
      Ob[(size_t)qrow * DMODEL + h * HD + c * 16 + lr] = (__bf16)val;
    }
  }
}

// ---------------- launch ----------------

extern "C" void kernel_launch(void* const* d_in, const int* in_sizes, int n_in,
                              void* d_out, int out_size, void* d_ws, size_t ws_size,
                              hipStream_t stream) {
  const float* x    = (const float*)d_in[0];
  const float* pk   = (const float*)d_in[1];
  const float* pv   = (const float*)d_in[2];
  const float* Wq   = (const float*)d_in[3];
  const float* bq   = (const float*)d_in[4];
  const float* Wk   = (const float*)d_in[5];
  const float* bk   = (const float*)d_in[6];
  const float* Wv   = (const float*)d_in[7];
  const float* bv   = (const float*)d_in[8];
  const float* gate = (const float*)d_in[9];
  const float* Wout = (const float*)d_in[10];
  const float* bout = (const float*)d_in[11];
  float* out = (float*)d_out;

  char* ws = (char*)d_ws;
  size_t off = 0;
  auto alc = [&](size_t elems) -> __bf16* {
    __bf16* p = (__bf16*)(ws + off);
    off += elems * 2;
    off = (off + 255) & ~(size_t)255;
    return p;
  };
  __bf16* xb   = alc((size_t)DMODEL * DMODEL);
  __bf16* WqT  = alc((size_t)DMODEL * DMODEL);
  __bf16* WkT  = alc((size_t)DMODEL * DMODEL);
  __bf16* WvT  = alc((size_t)DMODEL * DMODEL);
  __bf16* WoT  = alc((size_t)DMODEL * DMODEL);
  __bf16* Qs   = alc((size_t)NH * QLEN * HD);
  __bf16* Kall = alc((size_t)NH * KVLEN * HD);
  __bf16* VTa  = alc((size_t)NH * HD * KVLEN);
  __bf16* Ob   = alc((size_t)QLEN * DMODEL);

  dim3 tgrid(32, 32);
  k_transpose_bf16<<<tgrid, 256, 0, stream>>>(Wq, WqT);
  k_transpose_bf16<<<tgrid, 256, 0, stream>>>(Wk, WkT);
  k_transpose_bf16<<<tgrid, 256, 0, stream>>>(Wv, WvT);
  k_transpose_bf16<<<tgrid, 256, 0, stream>>>(Wout, WoT);
  k_f32_to_bf16<<<1024, 256, 0, stream>>>(x, xb, (DMODEL * DMODEL) / 4);
  k_prefix<<<4096, 256, 0, stream>>>(pk, pv, Kall, VTa);

  gemm_qkv<<<dim3(16, 16, 3), 256, 0, stream>>>(xb, WqT, WkT, WvT, bq, bk, bv, Qs, Kall, VTa);
  k_attn<<<dim3(32, 16), 256, 0, stream>>>(Qs, Kall, VTa, gate, Ob);
  gemm_out<<<dim3(16, 16), 256, 0, stream>>>(Ob, WoT, bout, out);
}

// Round 2
// 429.462 us; speedup vs baseline: 1.0478x; 1.0478x over previous
//
#include <hip/hip_runtime.h>
#include <hip/hip_bf16.h>

typedef __bf16 bf16x8 __attribute__((ext_vector_type(8)));
typedef __bf16 bf16x4v __attribute__((ext_vector_type(4)));
typedef float f32x4 __attribute__((ext_vector_type(4)));

#define DMODEL 2048
#define NH 16
#define HD 128
#define PLEN 512
#define QLEN 2048
#define KVLEN 2560

__device__ __forceinline__ void gload_lds16(const void* g, void* l) {
  __builtin_amdgcn_global_load_lds((const __attribute__((address_space(1))) void*)g,
                                   (__attribute__((address_space(3))) void*)l, 16, 0, 0);
}

// ---------------- conversion kernels ----------------

// f32 [2048][2048] row-major -> bf16 transposed [2048][2048]
__global__ __launch_bounds__(256) void k_transpose_bf16(const float* __restrict__ in,
                                                        __bf16* __restrict__ out) {
  __shared__ float tile[64][65];
  const int t = threadIdx.x;
  const int tx = t & 63, ty = t >> 6;
  const int r0 = blockIdx.y * 64, c0 = blockIdx.x * 64;
#pragma unroll
  for (int i = 0; i < 16; ++i) {
    int r = ty + i * 4;
    tile[r][tx] = in[(size_t)(r0 + r) * DMODEL + c0 + tx];
  }
  __syncthreads();
#pragma unroll
  for (int i = 0; i < 16; ++i) {
    int r = ty + i * 4;
    out[(size_t)(c0 + r) * DMODEL + r0 + tx] = (__bf16)tile[tx][r];
  }
}

__global__ __launch_bounds__(256) void k_f32_to_bf16(const float* __restrict__ in,
                                                     __bf16* __restrict__ out, int n4) {
  int i = blockIdx.x * blockDim.x + threadIdx.x;
  int stride = gridDim.x * blockDim.x;
  for (; i < n4; i += stride) {
    float4 v = ((const float4*)in)[i];
    bf16x4v o;
    o[0] = (__bf16)v.x; o[1] = (__bf16)v.y; o[2] = (__bf16)v.z; o[3] = (__bf16)v.w;
    ((bf16x4v*)out)[i] = o;
  }
}

// prefix_key/value f32 [512][16][128] -> K[h][p][hd], VT[h][hd][p]  (bf16)
__global__ __launch_bounds__(256) void k_prefix(const float* __restrict__ pk,
                                                const float* __restrict__ pv,
                                                __bf16* __restrict__ Kall,
                                                __bf16* __restrict__ VT) {
  int idx = blockIdx.x * 256 + threadIdx.x;  // 512*16*128 = 1048576 exact
  int hd = idx & 127;
  int h = (idx >> 7) & 15;
  int p = idx >> 11;
  Kall[(size_t)h * KVLEN * HD + (size_t)p * HD + hd] = (__bf16)pk[idx];
  VT[(size_t)h * HD * KVLEN + (size_t)hd * KVLEN + p] = (__bf16)pv[idx];
}

// ---------------- GEMM: C[128x128] = A[M,K] * BT[N,K]^T ----------------

__device__ __forceinline__ void gemm_mainloop(const __bf16* __restrict__ A,
                                              const __bf16* __restrict__ BT,
                                              __bf16* Asm, __bf16* Bsm,
                                              int m0, int n0, int w, int l,
                                              f32x4 (&acc)[4][4]) {
  const int lr = l & 15, lg = l >> 4;
  const int lin0 = w * 2048 + l * 16;      // byte offset in 8KB tile
  const int rowS = lin0 >> 6;              // 64B per row (32 bf16)
  const int colS = (lin0 & 63) >> 1;       // element offset within row
  for (int k0 = 0; k0 < DMODEL; k0 += 32) {
    __syncthreads();
#pragma unroll
    for (int i = 0; i < 2; ++i) {
      const __bf16* ga = A + (size_t)(m0 + rowS + i * 16) * DMODEL + k0 + colS;
      gload_lds16(ga, (char*)Asm + w * 2048 + i * 1024);
      const __bf16* gb = BT + (size_t)(n0 + rowS + i * 16) * DMODEL + k0 + colS;
      gload_lds16(gb, (char*)Bsm + w * 2048 + i * 1024);
    }
    __syncthreads();
    bf16x8 af[4], bfv[4];
#pragma unroll
    for (int mi = 0; mi < 4; ++mi)
      af[mi] = *(const bf16x8*)(Asm + ((w >> 1) * 64 + mi * 16 + lr) * 32 + lg * 8);
#pragma unroll
    for (int ni = 0; ni < 4; ++ni)
      bfv[ni] = *(const bf16x8*)(Bsm + ((w & 1) * 64 + ni * 16 + lr) * 32 + lg * 8);
#pragma unroll
    for (int mi = 0; mi < 4; ++mi)
#pragma unroll
      for (int ni = 0; ni < 4; ++ni)
        acc[mi][ni] = __builtin_amdgcn_mfma_f32_16x16x32_bf16(af[mi], bfv[ni], acc[mi][ni], 0, 0, 0);
  }
}

// z=0: Q (scaled 1/sqrt(128)) -> Qs[h][q][hd]; z=1: K -> Kall[h][512+q][hd]; z=2: V -> VT[h][hd][512+q]
__global__ __launch_bounds__(256) void gemm_qkv(const __bf16* __restrict__ xb,
                                                const __bf16* __restrict__ WqT,
                                                const __bf16* __restrict__ WkT,
                                                const __bf16* __restrict__ WvT,
                                                const float* __restrict__ bq,
                                                const float* __restrict__ bk,
                                                const float* __restrict__ bv,
                                                __bf16* __restrict__ Qs,
                                                __bf16* __restrict__ Kall,
                                                __bf16* __restrict__ VT) {
  __shared__ __bf16 Asm[4096];
  __shared__ __bf16 Bsm[4096];
  const int t = threadIdx.x, w = t >> 6, l = t & 63;
  const int m0 = blockIdx.x * 128, n0 = blockIdx.y * 128;
  const int z = blockIdx.z;
  const __bf16* BT = (z == 0) ? WqT : ((z == 1) ? WkT : WvT);
  const float* bias = (z == 0) ? bq : ((z == 1) ? bk : bv);
  f32x4 acc[4][4];
#pragma unroll
  for (int mi = 0; mi < 4; ++mi)
#pragma unroll
    for (int ni = 0; ni < 4; ++ni) acc[mi][ni] = (f32x4){0.f, 0.f, 0.f, 0.f};
  gemm_mainloop(xb, BT, Asm, Bsm, m0, n0, w, l, acc);
  const int lr = l & 15, lg = l >> 4;
#pragma unroll
  for (int mi = 0; mi < 4; ++mi)
#pragma unroll
    for (int ni = 0; ni < 4; ++ni)
#pragma unroll
      for (int r = 0; r < 4; ++r) {
        int row = m0 + (w >> 1) * 64 + mi * 16 + lg * 4 + r;
        int col = n0 + (w & 1) * 64 + ni * 16 + lr;
        float v = acc[mi][ni][r] + bias[col];
        int hh = col >> 7, hd = col & 127;
        if (z == 0) {
          Qs[(size_t)hh * QLEN * HD + (size_t)row * HD + hd] = (__bf16)(v * 0.08838834764831845f);
        } else if (z == 1) {
          Kall[(size_t)hh * KVLEN * HD + (size_t)(PLEN + row) * HD + hd] = (__bf16)v;
        } else {
          VT[(size_t)hh * HD * KVLEN + (size_t)hd * KVLEN + (PLEN + row)] = (__bf16)v;
        }
      }
}

// final: out[q][d] = O[q][:] . WoT[d][:] + bout[d]  (f32 out)
__global__ __launch_bounds__(256) void gemm_out(const __bf16* __restrict__ Ob,
                                                const __bf16* __restrict__ WoT,
                                                const float* __restrict__ bout,
                                                float* __restrict__ out) {
  __shared__ __bf16 Asm[4096];
  __shared__ __bf16 Bsm[4096];
  const int t = threadIdx.x, w = t >> 6, l = t & 63;
  const int m0 = blockIdx.x * 128, n0 = blockIdx.y * 128;
  f32x4 acc[4][4];
#pragma unroll
  for (int mi = 0; mi < 4; ++mi)
#pragma unroll
    for (int ni = 0; ni < 4; ++ni) acc[mi][ni] = (f32x4){0.f, 0.f, 0.f, 0.f};
  gemm_mainloop(Ob, WoT, Asm, Bsm, m0, n0, w, l, acc);
  const int lr = l & 15, lg = l >> 4;
#pragma unroll
  for (int mi = 0; mi < 4; ++mi)
#pragma unroll
    for (int ni = 0; ni < 4; ++ni)
#pragma unroll
      for (int r = 0; r < 4; ++r) {
        int row = m0 + (w >> 1) * 64 + mi * 16 + lg * 4 + r;
        int col = n0 + (w & 1) * 64 + ni * 16 + lr;
        out[(size_t)row * DMODEL + col] = acc[mi][ni][r] + bout[col];
      }
}

// ---------------- attention (K-split partial) ----------------
// grid (32, 16, KS): blockIdx.x = q-tile of 64 rows, y = head, z = key-parity split.
// 4 waves/block, each wave owns 16 q rows, processes key-tiles t ≡ z (mod KS).
// Fixed-max softmax (exp(S-16), |logit|<=~12 by Cauchy-Schwarz) => K-split partials
// combine by pure addition. Partial unnormalized acc (bf16) + row sums (f32) -> ws.
template <int KS>
__global__ __launch_bounds__(256) void k_attn(const __bf16* __restrict__ Qs,
                                              const __bf16* __restrict__ Kall,
                                              const __bf16* __restrict__ VT,
                                              __bf16* __restrict__ P1buf,
                                              float* __restrict__ S1buf,
                                              __bf16* __restrict__ P2buf,
                                              float* __restrict__ S2buf) {
  __shared__ __bf16 Pl[4][512];
  const int h = blockIdx.y;
  const int z = blockIdx.z;
  const int t = threadIdx.x, w = t >> 6, l = t & 63;
  const int lr = l & 15, lg = l >> 4;
  const int q0 = blockIdx.x * 64 + w * 16;
  const __bf16* Qh = Qs + (size_t)h * QLEN * HD;
  const __bf16* Kh = Kall + (size_t)h * KVLEN * HD;
  const __bf16* Vh = VT + (size_t)h * HD * KVLEN;
  __bf16* Pw = &Pl[w][0];

  bf16x8 qf[4];
#pragma unroll
  for (int c = 0; c < 4; ++c)
    qf[c] = *(const bf16x8*)(Qh + (size_t)(q0 + lr) * HD + c * 32 + lg * 8);

  f32x4 acc[8];
  float ss[4];

  // one 32-key tile: V loads issued FIRST (independent of QK/softmax) for ILP.
#define ATT_TILE(Kb, Vb, kb, DOMASK)                                                   \
  do {                                                                                 \
    bf16x8 vf[8];                                                                      \
    _Pragma("unroll") for (int c = 0; c < 8; ++c)                                      \
      vf[c] = *(const bf16x8*)((Vb) + (size_t)(c * 16 + lr) * KVLEN + (kb) + lg * 8);  \
    f32x4 st0 = {0.f, 0.f, 0.f, 0.f}, st1 = {0.f, 0.f, 0.f, 0.f};                      \
    _Pragma("unroll") for (int c = 0; c < 4; ++c) {                                    \
      bf16x8 kf0 = *(const bf16x8*)((Kb) + (size_t)((kb) + lr) * HD + c * 32 + lg * 8);\
      bf16x8 kf1 = *(const bf16x8*)((Kb) + (size_t)((kb) + 16 + lr) * HD + c * 32 + lg * 8); \
      st0 = __builtin_amdgcn_mfma_f32_16x16x32_bf16(qf[c], kf0, st0, 0, 0, 0);         \
      st1 = __builtin_amdgcn_mfma_f32_16x16x32_bf16(qf[c], kf1, st1, 0, 0, 0);         \
    }                                                                                  \
    _Pragma("unroll") for (int r = 0; r < 4; ++r) {                                    \
      if (DOMASK) {                                                                    \
        int qq = q0 + lg * 4 + r;                                                      \
        if ((kb) + lr > qq) st0[r] = -1e30f;                                           \
        if ((kb) + 16 + lr > qq) st1[r] = -1e30f;                                      \
      }                                                                                \
      float p0 = __expf(st0[r] - 16.0f);                                               \
      float p1 = __expf(st1[r] - 16.0f);                                               \
      ss[r] += p0 + p1;                                                                \
      Pw[(lg * 4 + r) * 32 + lr] = (__bf16)p0;                                         \
      Pw[(lg * 4 + r) * 32 + 16 + lr] = (__bf16)p1;                                    \
    }                                                                                  \
    bf16x8 pf = *(const bf16x8*)(Pw + lr * 32 + lg * 8);                               \
    _Pragma("unroll") for (int c = 0; c < 8; ++c)                                      \
      acc[c] = __builtin_amdgcn_mfma_f32_16x16x32_bf16(pf, vf[c], acc[c], 0, 0, 0);    \
  } while (0)

  // store phase partials: unnormalized acc (bf16) + lane-reduced sums (f32)
#define STORE_PHASE(PBUF, SBUF)                                                        \
  do {                                                                                 \
    const size_t rb = (size_t)(z * NH + h) * QLEN;                                     \
    _Pragma("unroll") for (int r = 0; r < 4; ++r) {                                    \
      float s = ss[r];                                                                 \
      s += __shfl_xor(s, 1); s += __shfl_xor(s, 2);                                    \
      s += __shfl_xor(s, 4); s += __shfl_xor(s, 8);                                    \
      const int row = q0 + lg * 4 + r;                                                 \
      if (lr == 0) SBUF[rb + row] = s;                                                 \
      _Pragma("unroll") for (int c = 0; c < 8; ++c)                                    \
        PBUF[(rb + row) * HD + c * 16 + lr] = (__bf16)acc[c][r];                       \
    }                                                                                  \
  } while (0)

  // ---- phase 1: prefix (16 tiles of 32 keys, unmasked), parity z ----
#pragma unroll
  for (int c = 0; c < 8; ++c) acc[c] = (f32x4){0.f, 0.f, 0.f, 0.f};
#pragma unroll
  for (int r = 0; r < 4; ++r) ss[r] = 0.f;
  for (int tt = z; tt < PLEN / 32; tt += KS) ATT_TILE(Kh, Vh, tt * 32, false);
  STORE_PHASE(P1buf, S1buf);

  // ---- phase 2: causal suffix, parity z ----
#pragma unroll
  for (int c = 0; c < 8; ++c) acc[c] = (f32x4){0.f, 0.f, 0.f, 0.f};
#pragma unroll
  for (int r = 0; r < 4; ++r) ss[r] = 0.f;
  const __bf16* Kh2 = Kh + (size_t)PLEN * HD;
  const __bf16* Vh2 = Vh + PLEN;
  const int ntile = (q0 + 47) >> 5;  // tiles with start <= q0+15
  for (int tt = z; tt < ntile; tt += KS) {
    const int kb = tt * 32;
    const bool dm = (kb + 31 > q0);
    ATT_TILE(Kh2, Vh2, kb, dm);
  }
  STORE_PHASE(P2buf, S2buf);
#undef ATT_TILE
#undef STORE_PHASE
}

// combine K-split partials: Ob = g*ΣP1/Σs1 + ΣP2/Σs2
template <int KS>
__global__ __launch_bounds__(256) void k_combine(const __bf16* __restrict__ P1buf,
                                                 const float* __restrict__ S1buf,
                                                 const __bf16* __restrict__ P2buf,
                                                 const float* __restrict__ S2buf,
                                                 const float* __restrict__ gate,
                                                 __bf16* __restrict__ Ob) {
  const int idx = blockIdx.x * 256 + threadIdx.x;  // 16*2048*128 total
  const int d = idx & 127;
  const int q = (idx >> 7) & 2047;
  const int h = idx >> 18;
  const size_t rq = (size_t)h * QLEN + q;
  float a1 = 0.f, a2 = 0.f, s1 = 0.f, s2 = 0.f;
#pragma unroll
  for (int zz = 0; zz < KS; ++zz) {
    const size_t zb = (size_t)zz * NH * QLEN;
    a1 += (float)P1buf[(zb + rq) * HD + d];
    a2 += (float)P2buf[(zb + rq) * HD + d];
    s1 += S1buf[zb + rq];
    s2 += S2buf[zb + rq];
  }
  float o = a1 * (gate[h] / s1) + a2 / s2;
  Ob[(size_t)q * DMODEL + h * HD + d] = (__bf16)o;
}

// ---------------- launch ----------------

extern "C" void kernel_launch(void* const* d_in, const int* in_sizes, int n_in,
                              void* d_out, int out_size, void* d_ws, size_t ws_size,
                              hipStream_t stream) {
  const float* x    = (const float*)d_in[0];
  const float* pk   = (const float*)d_in[1];
  const float* pv   = (const float*)d_in[2];
  const float* Wq   = (const float*)d_in[3];
  const float* bq   = (const float*)d_in[4];
  const float* Wk   = (const float*)d_in[5];
  const float* bk   = (const float*)d_in[6];
  const float* Wv   = (const float*)d_in[7];
  const float* bv   = (const float*)d_in[8];
  const float* gate = (const float*)d_in[9];
  const float* Wout = (const float*)d_in[10];
  const float* bout = (const float*)d_in[11];
  float* out = (float*)d_out;

  char* ws = (char*)d_ws;
  size_t off = 0;
  auto alc = [&](size_t bytes) -> char* {
    char* p = ws + off;
    off += bytes;
    off = (off + 255) & ~(size_t)255;
    return p;
  };
  __bf16* xb   = (__bf16*)alc((size_t)DMODEL * DMODEL * 2);
  __bf16* WqT  = (__bf16*)alc((size_t)DMODEL * DMODEL * 2);
  __bf16* WkT  = (__bf16*)alc((size_t)DMODEL * DMODEL * 2);
  __bf16* WvT  = (__bf16*)alc((size_t)DMODEL * DMODEL * 2);
  __bf16* WoT  = (__bf16*)alc((size_t)DMODEL * DMODEL * 2);
  __bf16* Qs   = (__bf16*)alc((size_t)NH * QLEN * HD * 2);
  __bf16* Kall = (__bf16*)alc((size_t)NH * KVLEN * HD * 2);
  __bf16* VTa  = (__bf16*)alc((size_t)NH * HD * KVLEN * 2);
  __bf16* Ob   = (__bf16*)alc((size_t)QLEN * DMODEL * 2);

  // K-split partial buffers; pick KS=2 if it fits, else KS=1 (deterministic in ws_size)
  const size_t per_split = (size_t)NH * QLEN * HD * 2 * 2   // P1+P2 bf16
                         + (size_t)NH * QLEN * 4 * 2 + 1024; // S1+S2 f32 + align slack
  int KS = (off + 2 * per_split <= ws_size) ? 2 : 1;
  __bf16* P1buf = (__bf16*)alc((size_t)KS * NH * QLEN * HD * 2);
  __bf16* P2buf = (__bf16*)alc((size_t)KS * NH * QLEN * HD * 2);
  float*  S1buf = (float*)alc((size_t)KS * NH * QLEN * 4);
  float*  S2buf = (float*)alc((size_t)KS * NH * QLEN * 4);

  dim3 tgrid(32, 32);
  k_transpose_bf16<<<tgrid, 256, 0, stream>>>(Wq, WqT);
  k_transpose_bf16<<<tgrid, 256, 0, stream>>>(Wk, WkT);
  k_transpose_bf16<<<tgrid, 256, 0, stream>>>(Wv, WvT);
  k_transpose_bf16<<<tgrid, 256, 0, stream>>>(Wout, WoT);
  k_f32_to_bf16<<<1024, 256, 0, stream>>>(x, xb, (DMODEL * DMODEL) / 4);
  k_prefix<<<4096, 256, 0, stream>>>(pk, pv, Kall, VTa);

  gemm_qkv<<<dim3(16, 16, 3), 256, 0, stream>>>(xb, WqT, WkT, WvT, bq, bk, bv, Qs, Kall, VTa);

  const int ncomb = (NH * QLEN * HD) / 256;
  if (KS == 2) {
    k_attn<2><<<dim3(32, 16, 2), 256, 0, stream>>>(Qs, Kall, VTa, P1buf, S1buf, P2buf, S2buf);
    k_combine<2><<<ncomb, 256, 0, stream>>>(P1buf, S1buf, P2buf, S2buf, gate, Ob);
  } else {
    k_attn<1><<<dim3(32, 16, 1), 256, 0, stream>>>(Qs, Kall, VTa, P1buf, S1buf, P2buf, S2buf);
    k_combine<1><<<ncomb, 256, 0, stream>>>(P1buf, S1buf, P2buf, S2buf, gate, Ob);
  }
  gemm_out<<<dim3(16, 16), 256, 0, stream>>>(Ob, WoT, bout, out);
}

// Round 3
// 227.094 us; speedup vs baseline: 1.9816x; 1.8911x over previous
//
#include <hip/hip_runtime.h>
#include <hip/hip_bf16.h>

typedef __bf16 bf16x8 __attribute__((ext_vector_type(8)));
typedef __bf16 bf16x4v __attribute__((ext_vector_type(4)));
typedef float f32x4 __attribute__((ext_vector_type(4)));

#define DMODEL 2048
#define NH 16
#define HD 128
#define PLEN 512
#define QLEN 2048
#define KVLEN 2560

__device__ __forceinline__ void gload_lds16(const void* g, void* l) {
  __builtin_amdgcn_global_load_lds((const __attribute__((address_space(1))) void*)g,
                                   (__attribute__((address_space(3))) void*)l, 16, 0, 0);
}

// ---------------- conversion kernels ----------------

// f32 [2048][2048] row-major -> bf16 transposed [2048][2048]
__global__ __launch_bounds__(256) void k_transpose_bf16(const float* __restrict__ in,
                                                        __bf16* __restrict__ out) {
  __shared__ float tile[64][65];
  const int t = threadIdx.x;
  const int tx = t & 63, ty = t >> 6;
  const int r0 = blockIdx.y * 64, c0 = blockIdx.x * 64;
#pragma unroll
  for (int i = 0; i < 16; ++i) {
    int r = ty + i * 4;
    tile[r][tx] = in[(size_t)(r0 + r) * DMODEL + c0 + tx];
  }
  __syncthreads();
#pragma unroll
  for (int i = 0; i < 16; ++i) {
    int r = ty + i * 4;
    out[(size_t)(c0 + r) * DMODEL + r0 + tx] = (__bf16)tile[tx][r];
  }
}

__global__ __launch_bounds__(256) void k_f32_to_bf16(const float* __restrict__ in,
                                                     __bf16* __restrict__ out, int n4) {
  int i = blockIdx.x * blockDim.x + threadIdx.x;
  int stride = gridDim.x * blockDim.x;
  for (; i < n4; i += stride) {
    float4 v = ((const float4*)in)[i];
    bf16x4v o;
    o[0] = (__bf16)v.x; o[1] = (__bf16)v.y; o[2] = (__bf16)v.z; o[3] = (__bf16)v.w;
    ((bf16x4v*)out)[i] = o;
  }
}

// prefix_key/value f32 [512][16][128] -> K[h][p][hd], VT[h][hd][p]  (bf16)
__global__ __launch_bounds__(256) void k_prefix(const float* __restrict__ pk,
                                                const float* __restrict__ pv,
                                                __bf16* __restrict__ Kall,
                                                __bf16* __restrict__ VT) {
  int idx = blockIdx.x * 256 + threadIdx.x;  // 512*16*128 = 1048576 exact
  int hd = idx & 127;
  int h = (idx >> 7) & 15;
  int p = idx >> 11;
  Kall[(size_t)h * KVLEN * HD + (size_t)p * HD + hd] = (__bf16)pk[idx];
  VT[(size_t)h * HD * KVLEN + (size_t)hd * KVLEN + p] = (__bf16)pv[idx];
}

// ---------------- GEMM: C[128x128] = A[M,K] * BT[N,K]^T ----------------

__device__ __forceinline__ void gemm_mainloop(const __bf16* __restrict__ A,
                                              const __bf16* __restrict__ BT,
                                              __bf16* Asm, __bf16* Bsm,
                                              int m0, int n0, int w, int l,
                                              f32x4 (&acc)[4][4]) {
  const int lr = l & 15, lg = l >> 4;
  const int lin0 = w * 2048 + l * 16;      // byte offset in 8KB tile
  const int rowS = lin0 >> 6;              // 64B per row (32 bf16)
  const int colS = (lin0 & 63) >> 1;       // element offset within row
  for (int k0 = 0; k0 < DMODEL; k0 += 32) {
    __syncthreads();
#pragma unroll
    for (int i = 0; i < 2; ++i) {
      const __bf16* ga = A + (size_t)(m0 + rowS + i * 16) * DMODEL + k0 + colS;
      gload_lds16(ga, (char*)Asm + w * 2048 + i * 1024);
      const __bf16* gb = BT + (size_t)(n0 + rowS + i * 16) * DMODEL + k0 + colS;
      gload_lds16(gb, (char*)Bsm + w * 2048 + i * 1024);
    }
    __syncthreads();
    bf16x8 af[4], bfv[4];
#pragma unroll
    for (int mi = 0; mi < 4; ++mi)
      af[mi] = *(const bf16x8*)(Asm + ((w >> 1) * 64 + mi * 16 + lr) * 32 + lg * 8);
#pragma unroll
    for (int ni = 0; ni < 4; ++ni)
      bfv[ni] = *(const bf16x8*)(Bsm + ((w & 1) * 64 + ni * 16 + lr) * 32 + lg * 8);
#pragma unroll
    for (int mi = 0; mi < 4; ++mi)
#pragma unroll
      for (int ni = 0; ni < 4; ++ni)
        acc[mi][ni] = __builtin_amdgcn_mfma_f32_16x16x32_bf16(af[mi], bfv[ni], acc[mi][ni], 0, 0, 0);
  }
}

// z=0: Q (scaled 1/sqrt(128)) -> Qs[h][q][hd]; z=1: K -> Kall[h][512+q][hd]; z=2: V -> VT[h][hd][512+q]
__global__ __launch_bounds__(256) void gemm_qkv(const __bf16* __restrict__ xb,
                                                const __bf16* __restrict__ WqT,
                                                const __bf16* __restrict__ WkT,
                                                const __bf16* __restrict__ WvT,
                                                const float* __restrict__ bq,
                                                const float* __restrict__ bk,
                                                const float* __restrict__ bv,
                                                __bf16* __restrict__ Qs,
                                                __bf16* __restrict__ Kall,
                                                __bf16* __restrict__ VT) {
  __shared__ __bf16 Asm[4096];
  __shared__ __bf16 Bsm[4096];
  const int t = threadIdx.x, w = t >> 6, l = t & 63;
  const int m0 = blockIdx.x * 128, n0 = blockIdx.y * 128;
  const int z = blockIdx.z;
  const __bf16* BT = (z == 0) ? WqT : ((z == 1) ? WkT : WvT);
  const float* bias = (z == 0) ? bq : ((z == 1) ? bk : bv);
  f32x4 acc[4][4];
#pragma unroll
  for (int mi = 0; mi < 4; ++mi)
#pragma unroll
    for (int ni = 0; ni < 4; ++ni) acc[mi][ni] = (f32x4){0.f, 0.f, 0.f, 0.f};
  gemm_mainloop(xb, BT, Asm, Bsm, m0, n0, w, l, acc);
  const int lr = l & 15, lg = l >> 4;
#pragma unroll
  for (int mi = 0; mi < 4; ++mi)
#pragma unroll
    for (int ni = 0; ni < 4; ++ni)
#pragma unroll
      for (int r = 0; r < 4; ++r) {
        int row = m0 + (w >> 1) * 64 + mi * 16 + lg * 4 + r;
        int col = n0 + (w & 1) * 64 + ni * 16 + lr;
        float v = acc[mi][ni][r] + bias[col];
        int hh = col >> 7, hd = col & 127;
        if (z == 0) {
          Qs[(size_t)hh * QLEN * HD + (size_t)row * HD + hd] = (__bf16)(v * 0.08838834764831845f);
        } else if (z == 1) {
          Kall[(size_t)hh * KVLEN * HD + (size_t)(PLEN + row) * HD + hd] = (__bf16)v;
        } else {
          VT[(size_t)hh * HD * KVLEN + (size_t)hd * KVLEN + (PLEN + row)] = (__bf16)v;
        }
      }
}

// final: out[q][d] = O[q][:] . WoT[d][:] + bout[d]  (f32 out)
__global__ __launch_bounds__(256) void gemm_out(const __bf16* __restrict__ Ob,
                                                const __bf16* __restrict__ WoT,
                                                const float* __restrict__ bout,
                                                float* __restrict__ out) {
  __shared__ __bf16 Asm[4096];
  __shared__ __bf16 Bsm[4096];
  const int t = threadIdx.x, w = t >> 6, l = t & 63;
  const int m0 = blockIdx.x * 128, n0 = blockIdx.y * 128;
  f32x4 acc[4][4];
#pragma unroll
  for (int mi = 0; mi < 4; ++mi)
#pragma unroll
    for (int ni = 0; ni < 4; ++ni) acc[mi][ni] = (f32x4){0.f, 0.f, 0.f, 0.f};
  gemm_mainloop(Ob, WoT, Asm, Bsm, m0, n0, w, l, acc);
  const int lr = l & 15, lg = l >> 4;
#pragma unroll
  for (int mi = 0; mi < 4; ++mi)
#pragma unroll
    for (int ni = 0; ni < 4; ++ni)
#pragma unroll
      for (int r = 0; r < 4; ++r) {
        int row = m0 + (w >> 1) * 64 + mi * 16 + lg * 4 + r;
        int col = n0 + (w & 1) * 64 + ni * 16 + lr;
        out[(size_t)row * DMODEL + col] = acc[mi][ni][r] + bout[col];
      }
}

// ---------------- attention (LDS-staged, double-buffered, K-split) ----------------
// grid (32, 16, KS): x = q-tile of 64 rows, y = head, z = key split (parity).
// 4 waves/block, wave w owns q rows [bx*64+w*16, +16). K/V tiles of 32 keys staged
// into LDS via global_load_lds (linear dest, pre-swizzled global source; XOR
// involutions: K o^=((o>>8)&7)<<4, V o^=((o>>7)&7)<<4 — rule both-sides-or-neither).
// T3-minimum pipeline: STAGE(next) || COMPUTE(cur); one barrier per tile.
// Fixed-max softmax exp(S-16) => K-split partials combine by pure addition.
template <int KS>
__global__ __launch_bounds__(256, 4) void k_attn(const __bf16* __restrict__ Qs,
                                                 const __bf16* __restrict__ Kall,
                                                 const __bf16* __restrict__ VT,
                                                 __bf16* __restrict__ P1buf,
                                                 float* __restrict__ S1buf,
                                                 __bf16* __restrict__ P2buf,
                                                 float* __restrict__ S2buf) {
  __shared__ __bf16 Ksm[2][4096];  // [buf][32 kv][128 hd]  (8KB each)
  __shared__ __bf16 Vsm[2][4096];  // [buf][128 hd][32 kv]  (8KB each)
  __shared__ __bf16 Pl[4][512];    // per-wave P tile [16 q][32 kv]
  const int h = blockIdx.y, z = blockIdx.z, bx = blockIdx.x;
  const int t = threadIdx.x, w = t >> 6, l = t & 63;
  const int lr = l & 15, lg = l >> 4;
  const int q0 = bx * 64 + w * 16;
  const __bf16* Qh = Qs + (size_t)h * QLEN * HD;
  const char* Khb = (const char*)(Kall + (size_t)h * KVLEN * HD);
  const char* Vhb = (const char*)(VT + (size_t)h * HD * KVLEN);
  __bf16* Pw = &Pl[w][0];

  bf16x8 qf[4];
#pragma unroll
  for (int c = 0; c < 4; ++c)
    qf[c] = *(const bf16x8*)(Qh + (size_t)(q0 + lr) * HD + c * 32 + lg * 8);

  f32x4 acc[8];
  float ss[4];

  // stage 32-key tile starting at global key index kb into buffer `buf`
  auto STAGE = [&](int buf, int kb) {
#pragma unroll
    for (int i = 0; i < 2; ++i) {  // K: 8KB, globally contiguous rows
      int o = (i * 256 + w * 64 + l) * 16;
      int po = o ^ (((o >> 8) & 7) << 4);
      gload_lds16(Khb + (size_t)kb * 256 + po, (char*)&Ksm[buf][0] + i * 4096 + w * 1024);
    }
#pragma unroll
    for (int i = 0; i < 2; ++i) {  // V: 8KB, rows strided KVLEN*2 in global VT
      int o = (i * 256 + w * 64 + l) * 16;
      int po = o ^ (((o >> 7) & 7) << 4);
      int row = po >> 6, colb = po & 63;
      gload_lds16(Vhb + (size_t)row * (KVLEN * 2) + (size_t)kb * 2 + colb,
                  (char*)&Vsm[buf][0] + i * 4096 + w * 1024);
    }
  };

  // compute one staged tile; mrel = suffix-relative key base (only used if domask)
  auto COMPUTE = [&](int buf, int mrel, bool domask) {
    const char* Kb = (const char*)&Ksm[buf][0];
    const char* Vb = (const char*)&Vsm[buf][0];
    f32x4 st0 = {0.f, 0.f, 0.f, 0.f}, st1 = {0.f, 0.f, 0.f, 0.f};
#pragma unroll
    for (int c = 0; c < 4; ++c) {
      int o0 = lr * 256 + c * 64 + lg * 16;        o0 ^= ((o0 >> 8) & 7) << 4;
      int o1 = (16 + lr) * 256 + c * 64 + lg * 16; o1 ^= ((o1 >> 8) & 7) << 4;
      bf16x8 kf0 = *(const bf16x8*)(Kb + o0);
      bf16x8 kf1 = *(const bf16x8*)(Kb + o1);
      st0 = __builtin_amdgcn_mfma_f32_16x16x32_bf16(qf[c], kf0, st0, 0, 0, 0);
      st1 = __builtin_amdgcn_mfma_f32_16x16x32_bf16(qf[c], kf1, st1, 0, 0, 0);
    }
#pragma unroll
    for (int r = 0; r < 4; ++r) {
      if (domask) {
        int qq = q0 + lg * 4 + r;
        if (mrel + lr > qq) st0[r] = -1e30f;
        if (mrel + 16 + lr > qq) st1[r] = -1e30f;
      }
      float p0 = __expf(st0[r] - 16.0f);
      float p1 = __expf(st1[r] - 16.0f);
      ss[r] += p0 + p1;
      Pw[(lg * 4 + r) * 32 + lr] = (__bf16)p0;
      Pw[(lg * 4 + r) * 32 + 16 + lr] = (__bf16)p1;
    }
    bf16x8 pf = *(const bf16x8*)(Pw + lr * 32 + lg * 8);
#pragma unroll
    for (int c = 0; c < 8; ++c) {
      int o = (c * 16 + lr) * 64 + lg * 16; o ^= ((o >> 7) & 7) << 4;
      bf16x8 vf = *(const bf16x8*)(Vb + o);
      acc[c] = __builtin_amdgcn_mfma_f32_16x16x32_bf16(pf, vf, acc[c], 0, 0, 0);
    }
  };

  auto STORE_PHASE = [&](__bf16* PBUF, float* SBUF) {
    const size_t rb = (size_t)(z * NH + h) * QLEN;
#pragma unroll
    for (int r = 0; r < 4; ++r) {
      float s = ss[r];
      s += __shfl_xor(s, 1); s += __shfl_xor(s, 2);
      s += __shfl_xor(s, 4); s += __shfl_xor(s, 8);
      const int row = q0 + lg * 4 + r;
      if (lr == 0) SBUF[rb + row] = s;
#pragma unroll
      for (int c = 0; c < 8; ++c)
        PBUF[(rb + row) * HD + c * 16 + lr] = (__bf16)acc[c][r];
    }
  };

  // ---- phase 1: prefix (16/KS tiles, unmasked), keys tt*32, tt ≡ z (mod KS) ----
#pragma unroll
  for (int c = 0; c < 8; ++c) acc[c] = (f32x4){0.f, 0.f, 0.f, 0.f};
#pragma unroll
  for (int r = 0; r < 4; ++r) ss[r] = 0.f;
  constexpr int NT1 = (PLEN / 32) / KS;
  int cur = 0;
  STAGE(0, z * 32);
  __syncthreads();
  for (int i = 0; i < NT1; ++i) {
    if (i + 1 < NT1) STAGE(cur ^ 1, (z + (i + 1) * KS) * 32);
    COMPUTE(cur, 0, false);
    __syncthreads();
    cur ^= 1;
  }
  // phase-2 prologue overlapped with phase-1 store
  STAGE(0, PLEN + z * 32);
  STORE_PHASE(P1buf, S1buf);

  // ---- phase 2: causal suffix, block-uniform tile count (extra tiles fully masked) ----
#pragma unroll
  for (int c = 0; c < 8; ++c) acc[c] = (f32x4){0.f, 0.f, 0.f, 0.f};
#pragma unroll
  for (int r = 0; r < 4; ++r) ss[r] = 0.f;
  const int ntb = 2 * bx + 2;                 // tiles needed by the block's highest wave
  const int n2 = (ntb - z + KS - 1) / KS;     // this split's tile count (>=1)
  cur = 0;
  __syncthreads();
  for (int i = 0; i < n2; ++i) {
    const int tt = z + i * KS;
    if (i + 1 < n2) STAGE(cur ^ 1, PLEN + (z + (i + 1) * KS) * 32);
    COMPUTE(cur, tt * 32, tt * 32 + 31 > q0);
    __syncthreads();
    cur ^= 1;
  }
  STORE_PHASE(P2buf, S2buf);
}

// combine K-split partials: Ob = g*ΣP1/Σs1 + ΣP2/Σs2
template <int KS>
__global__ __launch_bounds__(256) void k_combine(const __bf16* __restrict__ P1buf,
                                                 const float* __restrict__ S1buf,
                                                 const __bf16* __restrict__ P2buf,
                                                 const float* __restrict__ S2buf,
                                                 const float* __restrict__ gate,
                                                 __bf16* __restrict__ Ob) {
  const int idx = blockIdx.x * 256 + threadIdx.x;  // 16*2048*128 total
  const int d = idx & 127;
  const int q = (idx >> 7) & 2047;
  const int h = idx >> 18;
  const size_t rq = (size_t)h * QLEN + q;
  float a1 = 0.f, a2 = 0.f, s1 = 0.f, s2 = 0.f;
#pragma unroll
  for (int zz = 0; zz < KS; ++zz) {
    const size_t zb = (size_t)zz * NH * QLEN;
    a1 += (float)P1buf[(zb + rq) * HD + d];
    a2 += (float)P2buf[(zb + rq) * HD + d];
    s1 += S1buf[zb + rq];
    s2 += S2buf[zb + rq];
  }
  float o = a1 * (gate[h] / s1) + a2 / s2;
  Ob[(size_t)q * DMODEL + h * HD + d] = (__bf16)o;
}

// ---------------- launch ----------------

extern "C" void kernel_launch(void* const* d_in, const int* in_sizes, int n_in,
                              void* d_out, int out_size, void* d_ws, size_t ws_size,
                              hipStream_t stream) {
  const float* x    = (const float*)d_in[0];
  const float* pk   = (const float*)d_in[1];
  const float* pv   = (const float*)d_in[2];
  const float* Wq   = (const float*)d_in[3];
  const float* bq   = (const float*)d_in[4];
  const float* Wk   = (const float*)d_in[5];
  const float* bk   = (const float*)d_in[6];
  const float* Wv   = (const float*)d_in[7];
  const float* bv   = (const float*)d_in[8];
  const float* gate = (const float*)d_in[9];
  const float* Wout = (const float*)d_in[10];
  const float* bout = (const float*)d_in[11];
  float* out = (float*)d_out;

  char* ws = (char*)d_ws;
  size_t off = 0;
  auto alc = [&](size_t bytes) -> char* {
    char* p = ws + off;
    off += bytes;
    off = (off + 255) & ~(size_t)255;
    return p;
  };
  __bf16* xb   = (__bf16*)alc((size_t)DMODEL * DMODEL * 2);
  __bf16* WqT  = (__bf16*)alc((size_t)DMODEL * DMODEL * 2);
  __bf16* WkT  = (__bf16*)alc((size_t)DMODEL * DMODEL * 2);
  __bf16* WvT  = (__bf16*)alc((size_t)DMODEL * DMODEL * 2);
  __bf16* WoT  = (__bf16*)alc((size_t)DMODEL * DMODEL * 2);
  __bf16* Qs   = (__bf16*)alc((size_t)NH * QLEN * HD * 2);
  __bf16* Kall = (__bf16*)alc((size_t)NH * KVLEN * HD * 2);
  __bf16* VTa  = (__bf16*)alc((size_t)NH * HD * KVLEN * 2);
  __bf16* Ob   = (__bf16*)alc((size_t)QLEN * DMODEL * 2);

  // K-split partial buffers; pick KS=2 if it fits, else KS=1 (deterministic in ws_size)
  const size_t per_split = (size_t)NH * QLEN * HD * 2 * 2   // P1+P2 bf16
                         + (size_t)NH * QLEN * 4 * 2 + 1024; // S1+S2 f32 + align slack
  int KS = (off + 2 * per_split <= ws_size) ? 2 : 1;
  __bf16* P1buf = (__bf16*)alc((size_t)KS * NH * QLEN * HD * 2);
  __bf16* P2buf = (__bf16*)alc((size_t)KS * NH * QLEN * HD * 2);
  float*  S1buf = (float*)alc((size_t)KS * NH * QLEN * 4);
  float*  S2buf = (float*)alc((size_t)KS * NH * QLEN * 4);

  dim3 tgrid(32, 32);
  k_transpose_bf16<<<tgrid, 256, 0, stream>>>(Wq, WqT);
  k_transpose_bf16<<<tgrid, 256, 0, stream>>>(Wk, WkT);
  k_transpose_bf16<<<tgrid, 256, 0, stream>>>(Wv, WvT);
  k_transpose_bf16<<<tgrid, 256, 0, stream>>>(Wout, WoT);
  k_f32_to_bf16<<<1024, 256, 0, stream>>>(x, xb, (DMODEL * DMODEL) / 4);
  k_prefix<<<4096, 256, 0, stream>>>(pk, pv, Kall, VTa);

  gemm_qkv<<<dim3(16, 16, 3), 256, 0, stream>>>(xb, WqT, WkT, WvT, bq, bk, bv, Qs, Kall, VTa);

  const int ncomb = (NH * QLEN * HD) / 256;
  if (KS == 2) {
    k_attn<2><<<dim3(32, 16, 2), 256, 0, stream>>>(Qs, Kall, VTa, P1buf, S1buf, P2buf, S2buf);
    k_combine<2><<<ncomb, 256, 0, stream>>>(P1buf, S1buf, P2buf, S2buf, gate, Ob);
  } else {
    k_attn<1><<<dim3(32, 16, 1), 256, 0, stream>>>(Qs, Kall, VTa, P1buf, S1buf, P2buf, S2buf);
    k_combine<1><<<ncomb, 256, 0, stream>>>(P1buf, S1buf, P2buf, S2buf, gate, Ob);
  }
  gemm_out<<<dim3(16, 16), 256, 0, stream>>>(Ob, WoT, bout, out);
}

// Round 4
// 221.124 us; speedup vs baseline: 2.0351x; 1.0270x over previous
//
#include <hip/hip_runtime.h>
#include <hip/hip_bf16.h>

typedef __bf16 bf16x8 __attribute__((ext_vector_type(8)));
typedef __bf16 bf16x4v __attribute__((ext_vector_type(4)));
typedef float f32x4 __attribute__((ext_vector_type(4)));

#define DMODEL 2048
#define NH 16
#define HD 128
#define PLEN 512
#define QLEN 2048
#define KVLEN 2560

__device__ __forceinline__ void gload_lds16(const void* g, void* l) {
  __builtin_amdgcn_global_load_lds((const __attribute__((address_space(1))) void*)g,
                                   (__attribute__((address_space(3))) void*)l, 16, 0, 0);
}

// ---------------- conversion kernels ----------------

// f32 [2048][2048] row-major -> bf16 transposed [2048][2048]
__global__ __launch_bounds__(256) void k_transpose_bf16(const float* __restrict__ in,
                                                        __bf16* __restrict__ out) {
  __shared__ float tile[64][65];
  const int t = threadIdx.x;
  const int tx = t & 63, ty = t >> 6;
  const int r0 = blockIdx.y * 64, c0 = blockIdx.x * 64;
#pragma unroll
  for (int i = 0; i < 16; ++i) {
    int r = ty + i * 4;
    tile[r][tx] = in[(size_t)(r0 + r) * DMODEL + c0 + tx];
  }
  __syncthreads();
#pragma unroll
  for (int i = 0; i < 16; ++i) {
    int r = ty + i * 4;
    out[(size_t)(c0 + r) * DMODEL + r0 + tx] = (__bf16)tile[tx][r];
  }
}

__global__ __launch_bounds__(256) void k_f32_to_bf16(const float* __restrict__ in,
                                                     __bf16* __restrict__ out, int n4) {
  int i = blockIdx.x * blockDim.x + threadIdx.x;
  int stride = gridDim.x * blockDim.x;
  for (; i < n4; i += stride) {
    float4 v = ((const float4*)in)[i];
    bf16x4v o;
    o[0] = (__bf16)v.x; o[1] = (__bf16)v.y; o[2] = (__bf16)v.z; o[3] = (__bf16)v.w;
    ((bf16x4v*)out)[i] = o;
  }
}

// prefix_key/value f32 [512][16][128] -> K[h][p][hd], VT[h][hd][p]  (bf16)
__global__ __launch_bounds__(256) void k_prefix(const float* __restrict__ pk,
                                                const float* __restrict__ pv,
                                                __bf16* __restrict__ Kall,
                                                __bf16* __restrict__ VT) {
  int idx = blockIdx.x * 256 + threadIdx.x;  // 512*16*128 = 1048576 exact
  int hd = idx & 127;
  int h = (idx >> 7) & 15;
  int p = idx >> 11;
  Kall[(size_t)h * KVLEN * HD + (size_t)p * HD + hd] = (__bf16)pk[idx];
  VT[(size_t)h * HD * KVLEN + (size_t)hd * KVLEN + p] = (__bf16)pv[idx];
}

// ---------------- GEMM: C[128 x BN] = A[M,K] * BT[N,K]^T, double-buffered ----------------
// 4 waves; wave (w>>1, w&1) owns a 64 x (BN/2) quadrant. BK=32.
// T3-minimum pipeline: STAGE(next buf) issued BEFORE compute(cur); one barrier/iter.

template <int BN>
__device__ __forceinline__ void stage_tile(const __bf16* __restrict__ A,
                                           const __bf16* __restrict__ BT,
                                           char* AsmB, char* BsmB,
                                           int m0, int n0, int k0, int w, int l) {
#pragma unroll
  for (int i = 0; i < 2; ++i) {  // A: 128x32 bf16 = 8KB
    int base = i * 4096 + w * 1024;
    int o = base + l * 16;
    int row = o >> 6, col = (o & 63) >> 1;
    gload_lds16(A + (size_t)(m0 + row) * DMODEL + k0 + col, AsmB + base);
  }
  if constexpr (BN == 128) {
#pragma unroll
    for (int i = 0; i < 2; ++i) {  // B: 128x32 = 8KB
      int base = i * 4096 + w * 1024;
      int o = base + l * 16;
      int row = o >> 6, col = (o & 63) >> 1;
      gload_lds16(BT + (size_t)(n0 + row) * DMODEL + k0 + col, BsmB + base);
    }
  } else {  // BN==64: B: 64x32 = 4KB
    int base = w * 1024;
    int o = base + l * 16;
    int row = o >> 6, col = (o & 63) >> 1;
    gload_lds16(BT + (size_t)(n0 + row) * DMODEL + k0 + col, BsmB + base);
  }
}

template <int BN>
__device__ __forceinline__ void gemm_mainloop_db(const __bf16* __restrict__ A,
                                                 const __bf16* __restrict__ BT,
                                                 __bf16* Asm, __bf16* Bsm,  // [2][...]
                                                 int m0, int n0, int w, int l,
                                                 f32x4 (&acc)[4][BN / 32]) {
  constexpr int NI = BN / 32;
  constexpr int ABUF = 4096;           // elements per A buffer
  constexpr int BBUF = BN * 32;        // elements per B buffer
  const int lr = l & 15, lg = l >> 4;
  int cur = 0;
  stage_tile<BN>(A, BT, (char*)Asm, (char*)Bsm, m0, n0, 0, w, l);
  __syncthreads();
  for (int k0 = 0; k0 < DMODEL; k0 += 32) {
    if (k0 + 32 < DMODEL)
      stage_tile<BN>(A, BT, (char*)(Asm + (cur ^ 1) * ABUF), (char*)(Bsm + (cur ^ 1) * BBUF),
                     m0, n0, k0 + 32, w, l);
    const __bf16* Ab = Asm + cur * ABUF;
    const __bf16* Bb = Bsm + cur * BBUF;
    bf16x8 af[4], bfv[NI];
#pragma unroll
    for (int mi = 0; mi < 4; ++mi)
      af[mi] = *(const bf16x8*)(Ab + ((w >> 1) * 64 + mi * 16 + lr) * 32 + lg * 8);
#pragma unroll
    for (int ni = 0; ni < NI; ++ni)
      bfv[ni] = *(const bf16x8*)(Bb + ((w & 1) * (BN / 2) + ni * 16 + lr) * 32 + lg * 8);
    __builtin_amdgcn_s_setprio(1);
#pragma unroll
    for (int mi = 0; mi < 4; ++mi)
#pragma unroll
      for (int ni = 0; ni < NI; ++ni)
        acc[mi][ni] = __builtin_amdgcn_mfma_f32_16x16x32_bf16(af[mi], bfv[ni], acc[mi][ni], 0, 0, 0);
    __builtin_amdgcn_s_setprio(0);
    __syncthreads();
    cur ^= 1;
  }
}

// z=0: Q (scaled 1/sqrt(128)) -> Qs[h][q][hd]; z=1: K -> Kall[h][512+q][hd]; z=2: V -> VT[h][hd][512+q]
__global__ __launch_bounds__(256) void gemm_qkv(const __bf16* __restrict__ xb,
                                                const __bf16* __restrict__ WqT,
                                                const __bf16* __restrict__ WkT,
                                                const __bf16* __restrict__ WvT,
                                                const float* __restrict__ bq,
                                                const float* __restrict__ bk,
                                                const float* __restrict__ bv,
                                                __bf16* __restrict__ Qs,
                                                __bf16* __restrict__ Kall,
                                                __bf16* __restrict__ VT) {
  __shared__ __bf16 Asm[2][4096];
  __shared__ __bf16 Bsm[2][4096];
  const int t = threadIdx.x, w = t >> 6, l = t & 63;
  const int m0 = blockIdx.x * 128, n0 = blockIdx.y * 128;
  const int z = blockIdx.z;
  const __bf16* BT = (z == 0) ? WqT : ((z == 1) ? WkT : WvT);
  const float* bias = (z == 0) ? bq : ((z == 1) ? bk : bv);
  f32x4 acc[4][4];
#pragma unroll
  for (int mi = 0; mi < 4; ++mi)
#pragma unroll
    for (int ni = 0; ni < 4; ++ni) acc[mi][ni] = (f32x4){0.f, 0.f, 0.f, 0.f};
  gemm_mainloop_db<128>(xb, BT, &Asm[0][0], &Bsm[0][0], m0, n0, w, l, acc);
  const int lr = l & 15, lg = l >> 4;
#pragma unroll
  for (int mi = 0; mi < 4; ++mi)
#pragma unroll
    for (int ni = 0; ni < 4; ++ni)
#pragma unroll
      for (int r = 0; r < 4; ++r) {
        int row = m0 + (w >> 1) * 64 + mi * 16 + lg * 4 + r;
        int col = n0 + (w & 1) * 64 + ni * 16 + lr;
        float v = acc[mi][ni][r] + bias[col];
        int hh = col >> 7, hd = col & 127;
        if (z == 0) {
          Qs[(size_t)hh * QLEN * HD + (size_t)row * HD + hd] = (__bf16)(v * 0.08838834764831845f);
        } else if (z == 1) {
          Kall[(size_t)hh * KVLEN * HD + (size_t)(PLEN + row) * HD + hd] = (__bf16)v;
        } else {
          VT[(size_t)hh * HD * KVLEN + (size_t)hd * KVLEN + (PLEN + row)] = (__bf16)v;
        }
      }
}

// final: out[q][d] = O[q][:] . WoT[d][:] + bout[d]  (f32 out).  128x64 tile -> 512 blocks.
__global__ __launch_bounds__(256) void gemm_out(const __bf16* __restrict__ Ob,
                                                const __bf16* __restrict__ WoT,
                                                const float* __restrict__ bout,
                                                float* __restrict__ out) {
  __shared__ __bf16 Asm[2][4096];
  __shared__ __bf16 Bsm[2][2048];
  const int t = threadIdx.x, w = t >> 6, l = t & 63;
  const int m0 = blockIdx.x * 128, n0 = blockIdx.y * 64;
  f32x4 acc[4][2];
#pragma unroll
  for (int mi = 0; mi < 4; ++mi)
#pragma unroll
    for (int ni = 0; ni < 2; ++ni) acc[mi][ni] = (f32x4){0.f, 0.f, 0.f, 0.f};
  gemm_mainloop_db<64>(Ob, WoT, &Asm[0][0], &Bsm[0][0], m0, n0, w, l, acc);
  const int lr = l & 15, lg = l >> 4;
#pragma unroll
  for (int mi = 0; mi < 4; ++mi)
#pragma unroll
    for (int ni = 0; ni < 2; ++ni)
#pragma unroll
      for (int r = 0; r < 4; ++r) {
        int row = m0 + (w >> 1) * 64 + mi * 16 + lg * 4 + r;
        int col = n0 + (w & 1) * 32 + ni * 16 + lr;
        out[(size_t)row * DMODEL + col] = acc[mi][ni][r] + bout[col];
      }
}

// ---------------- attention (LDS-staged, double-buffered, balanced, fused epilogue) ----------------
// grid (32, 16): bx, head. qt = (h<8) ? bx : 31-bx  — pairs long+short q-tiles on the
// same CU under round-robin dispatch (blocks c and c+256 share bx). 4 waves/block,
// wave w owns q rows [qt*64 + w*16, +16). K/V tiles of 32 keys staged via
// global_load_lds (linear dest, pre-swizzled global source, XOR involutions).
// Fixed-max softmax exp(S-16) (|logit| <= ~12 by Cauchy-Schwarz after 1/sqrt(128) scaling).
// Both phases accumulate in registers; epilogue writes final Ob = g*acc1/s1 + acc2/s2.
__global__ __launch_bounds__(256, 2) void k_attn(const __bf16* __restrict__ Qs,
                                                 const __bf16* __restrict__ Kall,
                                                 const __bf16* __restrict__ VT,
                                                 const float* __restrict__ gate,
                                                 __bf16* __restrict__ Ob) {
  __shared__ __bf16 Ksm[2][4096];   // [buf][32 kv][128 hd]
  __shared__ __bf16 Vsm[2][4096];   // [buf][128 hd][32 kv]
  __shared__ __bf16 Pl[4][16 * 40]; // per-wave P tile [16 q][32 kv], stride 40 (bank-spread)
  const int h = blockIdx.y;
  const int qt = (h < 8) ? blockIdx.x : (31 - blockIdx.x);
  const int t = threadIdx.x, w = t >> 6, l = t & 63;
  const int lr = l & 15, lg = l >> 4;
  const int q0 = qt * 64 + w * 16;
  const __bf16* Qh = Qs + (size_t)h * QLEN * HD;
  const char* Khb = (const char*)(Kall + (size_t)h * KVLEN * HD);
  const char* Vhb = (const char*)(VT + (size_t)h * HD * KVLEN);
  __bf16* Pw = &Pl[w][0];

  bf16x8 qf[4];
#pragma unroll
  for (int c = 0; c < 4; ++c)
    qf[c] = *(const bf16x8*)(Qh + (size_t)(q0 + lr) * HD + c * 32 + lg * 8);

  f32x4 acc1[8], acc2[8];
  float ss1[4], ss2[4];
#pragma unroll
  for (int c = 0; c < 8; ++c) {
    acc1[c] = (f32x4){0.f, 0.f, 0.f, 0.f};
    acc2[c] = (f32x4){0.f, 0.f, 0.f, 0.f};
  }
#pragma unroll
  for (int r = 0; r < 4; ++r) { ss1[r] = 0.f; ss2[r] = 0.f; }

  // stage 32-key tile starting at absolute key index kb into buffer `buf`
  auto STAGE = [&](int buf, int kb) {
#pragma unroll
    for (int i = 0; i < 2; ++i) {  // K: 8KB, rows contiguous in global
      int o = (i * 256 + w * 64 + l) * 16;
      int po = o ^ (((o >> 8) & 7) << 4);
      gload_lds16(Khb + (size_t)kb * 256 + po, (char*)&Ksm[buf][0] + i * 4096 + w * 1024);
    }
#pragma unroll
    for (int i = 0; i < 2; ++i) {  // V: 8KB, rows strided KVLEN*2 in global VT
      int o = (i * 256 + w * 64 + l) * 16;
      int po = o ^ (((o >> 7) & 7) << 4);
      int row = po >> 6, colb = po & 63;
      gload_lds16(Vhb + (size_t)row * (KVLEN * 2) + (size_t)kb * 2 + colb,
                  (char*)&Vsm[buf][0] + i * 4096 + w * 1024);
    }
  };

  // compute one staged tile into (ACC, SS); mrel = suffix-relative key base for masking
  auto COMPUTE = [&](int buf, int mrel, bool domask, f32x4 (&ACC)[8], float (&SS)[4]) {
    const char* Kb = (const char*)&Ksm[buf][0];
    const char* Vb = (const char*)&Vsm[buf][0];
    f32x4 st0 = {0.f, 0.f, 0.f, 0.f}, st1 = {0.f, 0.f, 0.f, 0.f};
    __builtin_amdgcn_s_setprio(1);
#pragma unroll
    for (int c = 0; c < 4; ++c) {
      int o0 = lr * 256 + c * 64 + lg * 16;        o0 ^= ((o0 >> 8) & 7) << 4;
      int o1 = (16 + lr) * 256 + c * 64 + lg * 16; o1 ^= ((o1 >> 8) & 7) << 4;
      bf16x8 kf0 = *(const bf16x8*)(Kb + o0);
      bf16x8 kf1 = *(const bf16x8*)(Kb + o1);
      st0 = __builtin_amdgcn_mfma_f32_16x16x32_bf16(qf[c], kf0, st0, 0, 0, 0);
      st1 = __builtin_amdgcn_mfma_f32_16x16x32_bf16(qf[c], kf1, st1, 0, 0, 0);
    }
    __builtin_amdgcn_s_setprio(0);
#pragma unroll
    for (int r = 0; r < 4; ++r) {
      if (domask) {
        int qq = q0 + lg * 4 + r;
        if (mrel + lr > qq) st0[r] = -1e30f;
        if (mrel + 16 + lr > qq) st1[r] = -1e30f;
      }
      float p0 = __expf(st0[r] - 16.0f);
      float p1 = __expf(st1[r] - 16.0f);
      SS[r] += p0 + p1;
      Pw[(lg * 4 + r) * 40 + lr] = (__bf16)p0;
      Pw[(lg * 4 + r) * 40 + 16 + lr] = (__bf16)p1;
    }
    bf16x8 pf = *(const bf16x8*)(Pw + lr * 40 + lg * 8);
    __builtin_amdgcn_s_setprio(1);
#pragma unroll
    for (int c = 0; c < 8; ++c) {
      int o = (c * 16 + lr) * 64 + lg * 16; o ^= ((o >> 7) & 7) << 4;
      bf16x8 vf = *(const bf16x8*)(Vb + o);
      ACC[c] = __builtin_amdgcn_mfma_f32_16x16x32_bf16(pf, vf, ACC[c], 0, 0, 0);
    }
    __builtin_amdgcn_s_setprio(0);
  };

  // ---- phase 1: prefix, 16 tiles, unmasked ----
  int cur = 0;
  STAGE(0, 0);
  __syncthreads();
#pragma unroll 1
  for (int i = 0; i < PLEN / 32; ++i) {
    if (i + 1 < PLEN / 32) STAGE(cur ^ 1, (i + 1) * 32);
    COMPUTE(cur, 0, false, acc1, ss1);
    __syncthreads();
    cur ^= 1;
  }

  // ---- phase 2: causal suffix, block-uniform tile count (extra tiles fully masked) ----
  const int ntb = 2 * qt + 2;
  cur = 0;
  STAGE(0, PLEN);
  __syncthreads();
#pragma unroll 1
  for (int i = 0; i < ntb; ++i) {
    if (i + 1 < ntb) STAGE(cur ^ 1, PLEN + (i + 1) * 32);
    COMPUTE(cur, i * 32, i * 32 + 31 > q0, acc2, ss2);
    __syncthreads();
    cur ^= 1;
  }

  // ---- epilogue: Ob = gate*acc1/s1 + acc2/s2 ----
  const float g = gate[h];
#pragma unroll
  for (int r = 0; r < 4; ++r) {
    float s1 = ss1[r];
    s1 += __shfl_xor(s1, 1); s1 += __shfl_xor(s1, 2);
    s1 += __shfl_xor(s1, 4); s1 += __shfl_xor(s1, 8);
    float s2 = ss2[r];
    s2 += __shfl_xor(s2, 1); s2 += __shfl_xor(s2, 2);
    s2 += __shfl_xor(s2, 4); s2 += __shfl_xor(s2, 8);
    const float f1 = g / s1;
    const float f2 = 1.0f / s2;
    const int qrow = q0 + lg * 4 + r;
#pragma unroll
    for (int c = 0; c < 8; ++c) {
      float val = acc1[c][r] * f1 + acc2[c][r] * f2;
      Ob[(size_t)qrow * DMODEL + h * HD + c * 16 + lr] = (__bf16)val;
    }
  }
}

// ---------------- launch ----------------

extern "C" void kernel_launch(void* const* d_in, const int* in_sizes, int n_in,
                              void* d_out, int out_size, void* d_ws, size_t ws_size,
                              hipStream_t stream) {
  const float* x    = (const float*)d_in[0];
  const float* pk   = (const float*)d_in[1];
  const float* pv   = (const float*)d_in[2];
  const float* Wq   = (const float*)d_in[3];
  const float* bq   = (const float*)d_in[4];
  const float* Wk   = (const float*)d_in[5];
  const float* bk   = (const float*)d_in[6];
  const float* Wv   = (const float*)d_in[7];
  const float* bv   = (const float*)d_in[8];
  const float* gate = (const float*)d_in[9];
  const float* Wout = (const float*)d_in[10];
  const float* bout = (const float*)d_in[11];
  float* out = (float*)d_out;

  char* ws = (char*)d_ws;
  size_t off = 0;
  auto alc = [&](size_t bytes) -> char* {
    char* p = ws + off;
    off += bytes;
    off = (off + 255) & ~(size_t)255;
    return p;
  };
  __bf16* xb   = (__bf16*)alc((size_t)DMODEL * DMODEL * 2);
  __bf16* WqT  = (__bf16*)alc((size_t)DMODEL * DMODEL * 2);
  __bf16* WkT  = (__bf16*)alc((size_t)DMODEL * DMODEL * 2);
  __bf16* WvT  = (__bf16*)alc((size_t)DMODEL * DMODEL * 2);
  __bf16* WoT  = (__bf16*)alc((size_t)DMODEL * DMODEL * 2);
  __bf16* Qs   = (__bf16*)alc((size_t)NH * QLEN * HD * 2);
  __bf16* Kall = (__bf16*)alc((size_t)NH * KVLEN * HD * 2);
  __bf16* VTa  = (__bf16*)alc((size_t)NH * HD * KVLEN * 2);
  __bf16* Ob   = (__bf16*)alc((size_t)QLEN * DMODEL * 2);

  dim3 tgrid(32, 32);
  k_transpose_bf16<<<tgrid, 256, 0, stream>>>(Wq, WqT);
  k_transpose_bf16<<<tgrid, 256, 0, stream>>>(Wk, WkT);
  k_transpose_bf16<<<tgrid, 256, 0, stream>>>(Wv, WvT);
  k_transpose_bf16<<<tgrid, 256, 0, stream>>>(Wout, WoT);
  k_f32_to_bf16<<<1024, 256, 0, stream>>>(x, xb, (DMODEL * DMODEL) / 4);
  k_prefix<<<4096, 256, 0, stream>>>(pk, pv, Kall, VTa);

  gemm_qkv<<<dim3(16, 16, 3), 256, 0, stream>>>(xb, WqT, WkT, WvT, bq, bk, bv, Qs, Kall, VTa);
  k_attn<<<dim3(32, 16), 256, 0, stream>>>(Qs, Kall, VTa, gate, Ob);
  gemm_out<<<dim3(16, 32), 256, 0, stream>>>(Ob, WoT, bout, out);
}